// Round 7
// baseline (1745.445 us; speedup 1.0000x reference)
//
#include <hip/hip_runtime.h>
#include <stdint.h>

typedef __attribute__((ext_vector_type(4))) float f32x4;
typedef __attribute__((ext_vector_type(8))) _Float16 f16x8;

static __device__ __forceinline__ unsigned short f2h(float f) {
    union { _Float16 h; unsigned short u; } v;
    v.h = (_Float16)f;                      // v_cvt_f16_f32, RNE
    return v.u;
}
static __device__ __forceinline__ float h2f_lo(unsigned int u) {
    union { unsigned short s; _Float16 h; } v; v.s = (unsigned short)(u & 0xffffu);
    return (float)v.h;
}
static __device__ __forceinline__ float h2f_hi(unsigned int u) {
    union { unsigned short s; _Float16 h; } v; v.s = (unsigned short)(u >> 16);
    return (float)v.h;
}
static __device__ __forceinline__ f16x8 as_f16x8(uint4 v) {
    union { uint4 u; f16x8 s; } x; x.u = v; return x.s;
}
static __device__ __forceinline__ float sigmoid_fast(float x) {
    return __builtin_amdgcn_rcpf(1.0f + __builtin_amdgcn_exp2f(-1.4426950408889634f * x));
}
static __device__ __forceinline__ float tanh_fast(float x) {
    return 1.0f - 2.0f * __builtin_amdgcn_rcpf(1.0f + __builtin_amdgcn_exp2f(2.8853900817779268f * x));
}
// barrier that waits only LDS (lgkmcnt(0)), NOT vmcnt — global stores keep retiring async.
static __device__ __forceinline__ void lds_barrier() {
    __builtin_amdgcn_s_waitcnt(0xc07f);
    __builtin_amdgcn_s_barrier();
}

// ---------- fused fp32 -> fp16 conversion for all 6 tensors (1 dispatch) ----------
__global__ __launch_bounds__(256) void convert_all(
    const float* __restrict__ h, const float* __restrict__ c,
    const float* __restrict__ iWh, const float* __restrict__ iWc,
    const float* __restrict__ Wih, const float* __restrict__ Whh,
    unsigned short* __restrict__ hc_h, unsigned short* __restrict__ iWh_h,
    unsigned short* __restrict__ iWc_h, unsigned short* __restrict__ Wih_h,
    unsigned short* __restrict__ Whh_h) {
    int i = blockIdx.x * 256 + threadIdx.x;      // float4 index, total 589824
    const float* src; unsigned short* dst;
    if (i < 131072) {            // h -> hc[:, 0:512]
        int base = i * 4, r = base >> 9, cc = base & 511;
        src = h + base; dst = hc_h + r * 1024 + cc;
    } else if (i < 262144) {     // c -> hc[:, 512:1024]
        int j = i - 131072; int base = j * 4, r = base >> 9, cc = base & 511;
        src = c + base; dst = hc_h + r * 1024 + 512 + cc;
    } else if (i < 327680) { int j = i - 262144; src = iWh + j * 4; dst = iWh_h + j * 4; }
    else if (i < 393216)   { int j = i - 327680; src = iWc + j * 4; dst = iWc_h + j * 4; }
    else if (i < 524288)   { int j = i - 393216; src = Wih + j * 4; dst = Wih_h + j * 4; }
    else                   { int j = i - 524288; src = Whh + j * 4; dst = Whh_h + j * 4; }
    float4 v = *(const float4*)src;
    dst[0] = f2h(v.x); dst[1] = f2h(v.y); dst[2] = f2h(v.z); dst[3] = f2h(v.w);
}

// ---------- generic C[M,N] = A[M,lda] @ W[N,ldw(:K)]^T + bias (+ELU), fp16 in / fp32 out ----
__global__ __launch_bounds__(256) void gemm_bt(
    const unsigned short* __restrict__ A, const unsigned short* __restrict__ W,
    float* __restrict__ C, const float* __restrict__ b1, const float* __restrict__ b2,
    int K, int lda, int ldw, int N, int do_elu, int bias_row) {
    __shared__ unsigned short As[64][40];
    __shared__ unsigned short Bs[64][40];
    int tid = threadIdx.x;
    int lane = tid & 63, wv = tid >> 6;
    int q = lane >> 4, l15 = lane & 15;
    int Mbase = blockIdx.x * 64, Nbase = blockIdx.y * 64;
    int ldrow = tid >> 2, seg = tid & 3;
    const unsigned short* Ap = A + (size_t)(Mbase + ldrow) * lda + seg * 8;
    const unsigned short* Wp = W + (size_t)(Nbase + ldrow) * ldw + seg * 8;
    f32x4 acc[4] = {};
    for (int k0 = 0; k0 < K; k0 += 32) {
        uint4 av = *(const uint4*)(Ap + k0);
        uint4 wvv = *(const uint4*)(Wp + k0);
        __syncthreads();
        *(uint4*)(&As[ldrow][seg * 8]) = av;
        *(uint4*)(&Bs[ldrow][seg * 8]) = wvv;
        __syncthreads();
        f16x8 af = *(const f16x8*)(&As[wv * 16 + l15][q * 8]);
#pragma unroll
        for (int nt = 0; nt < 4; nt++) {
            f16x8 bf = *(const f16x8*)(&Bs[nt * 16 + l15][q * 8]);
            acc[nt] = __builtin_amdgcn_mfma_f32_16x16x32_f16(af, bf, acc[nt], 0, 0, 0);
        }
    }
#pragma unroll
    for (int nt = 0; nt < 4; nt++) {
        int col = Nbase + nt * 16 + l15;
        float bcol = bias_row ? 0.0f : (b1[col] + (b2 ? b2[col] : 0.0f));
#pragma unroll
        for (int r = 0; r < 4; r++) {
            int row = Mbase + wv * 16 + q * 4 + r;
            float bias = bias_row ? (b1[row] + (b2 ? b2[row] : 0.0f)) : bcol;
            float v = acc[nt][r] + bias;
            if (do_elu) v = v > 0.0f ? v : (__builtin_amdgcn_exp2f(1.4426950408889634f * v) - 1.0f);
            C[(size_t)row * N + col] = v;
        }
    }
}

// ---------- fused init-state GEMMs (h0 and c0 via blockIdx.z), K=1024, N=256, ELU ----------
__global__ __launch_bounds__(256) void gemm_init(
    const unsigned short* __restrict__ A,
    const unsigned short* __restrict__ W0, const unsigned short* __restrict__ W1,
    float* __restrict__ C0, float* __restrict__ C1,
    const float* __restrict__ bias0, const float* __restrict__ bias1) {
    const unsigned short* W = blockIdx.z ? W1 : W0;
    float* C = blockIdx.z ? C1 : C0;
    const float* bias = blockIdx.z ? bias1 : bias0;
    __shared__ unsigned short As[64][40];
    __shared__ unsigned short Bs[64][40];
    int tid = threadIdx.x;
    int lane = tid & 63, wv = tid >> 6;
    int q = lane >> 4, l15 = lane & 15;
    int Mbase = blockIdx.x * 64, Nbase = blockIdx.y * 64;
    int ldrow = tid >> 2, seg = tid & 3;
    const unsigned short* Ap = A + (size_t)(Mbase + ldrow) * 1024 + seg * 8;
    const unsigned short* Wp = W + (size_t)(Nbase + ldrow) * 1024 + seg * 8;
    f32x4 acc[4] = {};
    for (int k0 = 0; k0 < 1024; k0 += 32) {
        uint4 av = *(const uint4*)(Ap + k0);
        uint4 wvv = *(const uint4*)(Wp + k0);
        __syncthreads();
        *(uint4*)(&As[ldrow][seg * 8]) = av;
        *(uint4*)(&Bs[ldrow][seg * 8]) = wvv;
        __syncthreads();
        f16x8 af = *(const f16x8*)(&As[wv * 16 + l15][q * 8]);
#pragma unroll
        for (int nt = 0; nt < 4; nt++) {
            f16x8 bf = *(const f16x8*)(&Bs[nt * 16 + l15][q * 8]);
            acc[nt] = __builtin_amdgcn_mfma_f32_16x16x32_f16(af, bf, acc[nt], 0, 0, 0);
        }
    }
#pragma unroll
    for (int nt = 0; nt < 4; nt++) {
        int col = Nbase + nt * 16 + l15;
        float b = bias[col];
#pragma unroll
        for (int r = 0; r < 4; r++) {
            int row = Mbase + wv * 16 + q * 4 + r;
            float v = acc[nt][r] + b;
            v = v > 0.0f ? v : (__builtin_amdgcn_exp2f(1.4426950408889634f * v) - 1.0f);
            C[(size_t)row * 256 + col] = v;
        }
    }
}

// ---------- persistent recurrent kernel: 64 blocks x 512 thr, 16 rows/block ----------
// FULL Whh residency (47-reg/17-LDS per wave, r5/r6-verified) + PHASE OVERLAP:
//   r6 post-mortem: per-SIMD matrix-pipe time is ~2500 cyc/step (19 cyc per 16x16x32 MFMA
//   per SIMD, not 4.85 — that was the 4-SIMD full-CU figure), and the MFMA, VALU (element-
//   wise), and DS phases run back-to-back with no overlap (both waves barrier-locked into
//   the same phase). Fix: split K accumulation by output half (ct):
//     Phase A: ct=0 gates, 32 MFMAs, pure cluster, s_setprio(1).
//     Phase B: ct=1's 32 MFMAs with ct=0's elementwise + h-writes + out-stores interleaved
//              between MFMA chunks -> ~1200 cyc of VALU/DS hides under the matrix pipe.
//     Phase C: ct=1 elementwise + writes, then the single lgkm-only barrier.
//   Phase-B af reads go through an asm-opaque pointer so they re-read LDS (no CSE keeping
//   32 extra VGPRs live across A->B); +64KB/step LDS traffic, hidden under MFMA.
#define HB_STRIDE 264                    // fp16 elems per h row (33x16B)
#define HB_HALF   (16 * HB_STRIDE)      // one h buffer, elems
#define WLDS_OFF  (2 * HB_HALF * 2)     // bytes: 16896
#define WFRAGS    17                     // LDS weight frags per wave (1 KB each)
#define LSTM_LDS_BYTES (WLDS_OFF + 8 * WFRAGS * 1024)   // 156160 <= 163840

__global__ __launch_bounds__(512, 2) void lstm_rec(
    const unsigned short* __restrict__ Whh,   // [1024,256] fp16
    const float* __restrict__ xpT,            // [1024 gatecols, 1024 rows] fp32
    const float* __restrict__ h0,             // [1024,256]
    const float* __restrict__ c0,             // [1024,256]
    const int* __restrict__ seq_len,
    float* __restrict__ out)                  // [1024, T, 256]
{
    __shared__ uint4 smem4[LSTM_LDS_BYTES / 16];
    unsigned short* hbuf = (unsigned short*)smem4;           // [2][16][HB_STRIDE]
    unsigned char* wlds = (unsigned char*)smem4 + WLDS_OFF;  // 8 waves * 17 frags * 1 KB
    const int tid = threadIdx.x;
    const int lane = tid & 63, wv = tid >> 6;   // wv 0..7
    const int q = lane >> 4, l15 = lane & 15;
    const int T = *seq_len;
    const int rowbase = blockIdx.x * 16;

    {   // h0 -> hbuf[0] rows 0..15 as fp16 (512 thr * 8 elems = 16*256 exactly)
        int e = tid * 8;
        int r = e >> 8, cc = e & 255;
        const float* s = h0 + (size_t)(rowbase + r) * 256 + cc;
        float4 v0 = *(const float4*)s;
        float4 v1 = *(const float4*)(s + 4);
        unsigned short* d = hbuf + r * HB_STRIDE + cc;
        d[0] = f2h(v0.x); d[1] = f2h(v0.y); d[2] = f2h(v0.z); d[3] = f2h(v0.w);
        d[4] = f2h(v1.x); d[5] = f2h(v1.y); d[6] = f2h(v1.z); d[7] = f2h(v1.w);
    }

    // weight fragment (kt,g,ct): elem = g*65536 + wv*8192 + ct*4096 + l15*256 + kt*32 + q*8
    const unsigned short* wb = Whh + wv * 8192 + l15 * 256 + q * 8;

    // 47 frags -> registers (frag id fi = kt*8 + g*2 + ct, kt 0..5; fi==47 lives in LDS)
    uint4 wreg[47];
#pragma unroll
    for (int kt = 0; kt < 6; kt++)
#pragma unroll
        for (int g = 0; g < 4; g++)
#pragma unroll
            for (int ct = 0; ct < 2; ct++) {
                int fi = kt * 8 + g * 2 + ct;
                if (fi < 47)
                    wreg[fi] = *(const uint4*)(wb + (size_t)g * 65536 + ct * 4096 + kt * 32);
            }

    // 17 frags -> LDS: slots 0-7 = kt6, 8-15 = kt7, 16 = (kt5,g3,ct1); lane-linear 16B
    unsigned char* wlp = wlds + wv * (WFRAGS * 1024) + lane * 16;
#pragma unroll
    for (int fi = 0; fi < WFRAGS; fi++) {
        int kt = (fi < 8) ? 6 : (fi < 16 ? 7 : 5);
        int p  = (fi < 16) ? (fi & 7) : 7;
        int g = p >> 1, ct = p & 1;
        uint4 v = *(const uint4*)(wb + (size_t)g * 65536 + ct * 4096 + kt * 32);
        *(uint4*)(wlp + fi * 1024) = v;
    }

    // c0 -> 8 f32 regs
    float creg[8];
#pragma unroll
    for (int ct = 0; ct < 2; ct++)
#pragma unroll
        for (int r = 0; r < 4; r++)
            creg[ct * 4 + r] = c0[(size_t)(rowbase + q * 4 + r) * 256 + wv * 32 + ct * 16 + l15];

    // x-proj -> 16 packed-f16 regs (prologue only; per-step it's a VALU add after MFMA).
    unsigned int xph[16];
    {
        const float* xpb = xpT + (size_t)(wv * 32 + l15) * 1024 + rowbase + (q << 2);
#pragma unroll
        for (int p = 0; p < 8; p++) {
            f32x4 v = *(const f32x4*)(xpb + (size_t)(p >> 1) * 262144 + (p & 1) * 16384);
            xph[p * 2]     = (unsigned int)f2h(v[0]) | ((unsigned int)f2h(v[1]) << 16);
            xph[p * 2 + 1] = (unsigned int)f2h(v[2]) | ((unsigned int)f2h(v[3]) << 16);
        }
    }

    float* outp = out + ((size_t)(rowbase + q * 4) * T) * 256 + wv * 32 + l15;

    __syncthreads();

// elementwise + stores for one (ct, r) item; acc/creg/xph/hn/outp from scope; r literal
#define EW_STORE(ct, r) do { \
        const int w_ = (r) >> 1; \
        float xi = ((r) & 1) ? h2f_hi(xph[(0 + (ct)) * 2 + w_]) : h2f_lo(xph[(0 + (ct)) * 2 + w_]); \
        float xf = ((r) & 1) ? h2f_hi(xph[(2 + (ct)) * 2 + w_]) : h2f_lo(xph[(2 + (ct)) * 2 + w_]); \
        float xg = ((r) & 1) ? h2f_hi(xph[(4 + (ct)) * 2 + w_]) : h2f_lo(xph[(4 + (ct)) * 2 + w_]); \
        float xo = ((r) & 1) ? h2f_hi(xph[(6 + (ct)) * 2 + w_]) : h2f_lo(xph[(6 + (ct)) * 2 + w_]); \
        float ig = sigmoid_fast(acc[0 + (ct)][(r)] + xi); \
        float fg = sigmoid_fast(acc[2 + (ct)][(r)] + xf); \
        float gg = tanh_fast(acc[4 + (ct)][(r)] + xg); \
        float og = sigmoid_fast(acc[6 + (ct)][(r)] + xo); \
        float cn = fg * creg[(ct) * 4 + (r)] + ig * gg; \
        creg[(ct) * 4 + (r)] = cn; \
        float hv = og * tanh_fast(cn); \
        hn[(r) * HB_STRIDE + (ct) * 16] = f2h(hv); \
        outp[(size_t)(r) * T * 256 + (ct) * 16] = hv; \
    } while (0)

    for (int t = 0; t < T; t++) {
        const unsigned short* hb = hbuf + (t & 1) * HB_HALF + l15 * HB_STRIDE + q * 8;
        unsigned short* hn = hbuf + ((t + 1) & 1) * HB_HALF + (q * 4) * HB_STRIDE + wv * 32 + l15;
        const unsigned short* hb2 = hb;
        asm("" : "+v"(hb2));            // opaque alias: phase-B af loads re-read LDS (no CSE)

        f32x4 acc[8];
#pragma unroll
        for (int p = 0; p < 8; p++) {
            acc[p][0] = 0.0f; acc[p][1] = 0.0f; acc[p][2] = 0.0f; acc[p][3] = 0.0f;
        }

        // ---- Phase A: ct=0 gates (p even), all kt — pure MFMA cluster, high prio
        __builtin_amdgcn_s_setprio(1);
#pragma unroll
        for (int kt = 0; kt < 8; kt++) {
            f16x8 af = *(const f16x8*)(hb + kt * 32);
#pragma unroll
            for (int g = 0; g < 4; g++) {
                const int p = g * 2;               // ct = 0, never the (kt5,p7) special
                f16x8 bf;
                if (kt < 6)       bf = as_f16x8(wreg[kt * 8 + p]);
                else if (kt == 6) bf = *(const f16x8*)(wlp + p * 1024);
                else              bf = *(const f16x8*)(wlp + (8 + p) * 1024);
                acc[p] = __builtin_amdgcn_mfma_f32_16x16x32_f16(af, bf, acc[p], 0, 0, 0);
            }
        }
        __builtin_amdgcn_s_setprio(0);

        // ---- Phase B: ct=1 MFMAs with ct=0 elementwise/stores interleaved
#pragma unroll
        for (int kt = 0; kt < 8; kt++) {
            f16x8 af = *(const f16x8*)(hb2 + kt * 32);
#pragma unroll
            for (int g = 0; g < 4; g++) {
                const int p = g * 2 + 1;           // ct = 1
                f16x8 bf;
                if (kt < 6 && !(kt == 5 && p == 7)) bf = as_f16x8(wreg[kt * 8 + p]);
                else if (kt == 6) bf = *(const f16x8*)(wlp + p * 1024);
                else if (kt == 7) bf = *(const f16x8*)(wlp + (8 + p) * 1024);
                else              bf = *(const f16x8*)(wlp + 16 * 1024);   // kt5, p7
                acc[p] = __builtin_amdgcn_mfma_f32_16x16x32_f16(af, bf, acc[p], 0, 0, 0);
            }
            if (kt == 1) EW_STORE(0, 0);
            if (kt == 3) EW_STORE(0, 1);
            if (kt == 5) EW_STORE(0, 2);
            if (kt == 7) EW_STORE(0, 3);
        }

        // ---- Phase C: ct=1 elementwise + writes, then barrier
        EW_STORE(1, 0);
        EW_STORE(1, 1);
        EW_STORE(1, 2);
        EW_STORE(1, 3);

        outp += 256;
        lds_barrier();
    }
#undef EW_STORE
}

extern "C" void kernel_launch(void* const* d_in, const int* in_sizes, int n_in,
                              void* d_out, int out_size, void* d_ws, size_t ws_size,
                              hipStream_t stream) {
    const float* h   = (const float*)d_in[0];
    const float* c   = (const float*)d_in[1];
    const int*   seqp= (const int*)d_in[2];
    const float* iWh = (const float*)d_in[3];
    const float* ibh = (const float*)d_in[4];
    const float* iWc = (const float*)d_in[5];
    const float* ibc = (const float*)d_in[6];
    const float* Wih = (const float*)d_in[7];
    const float* Whh = (const float*)d_in[8];
    const float* bih = (const float*)d_in[9];
    const float* bhh = (const float*)d_in[10];
    float* out = (float*)d_out;
    unsigned char* ws = (unsigned char*)d_ws;

    // workspace layout (16B-aligned)
    unsigned short* hc_h  = (unsigned short*)(ws + 0);        // [1024,1024] fp16 = 2 MB
    unsigned short* iWh_h = (unsigned short*)(ws + 2097152);  // [256,1024]
    unsigned short* iWc_h = (unsigned short*)(ws + 2621440);  // [256,1024]
    unsigned short* Wih_h = (unsigned short*)(ws + 3145728);  // [1024,512]
    unsigned short* Whh_h = (unsigned short*)(ws + 4194304);  // [1024,256]
    float* h0  = (float*)(ws + 4718592);                       // [1024,256]
    float* c0  = (float*)(ws + 5767168);                       // [1024,256]
    float* xpT = (float*)(ws + 6815744);                       // [1024 gatecols,1024 rows]

    // fp16 conversions: all 6 tensors in one dispatch
    convert_all<<<2304, 256, 0, stream>>>(h, c, iWh, iWc, Wih, Whh,
                                          hc_h, iWh_h, iWc_h, Wih_h, Whh_h);

    // init states (fused pair) + transposed x_proj:
    // xpT[gatecol, batch] = Wih[gatecol,:] . h[batch,:] + bih[gatecol] + bhh[gatecol]
    gemm_init<<<dim3(16, 4, 2), 256, 0, stream>>>(hc_h, iWh_h, iWc_h, h0, c0, ibh, ibc);
    gemm_bt<<<dim3(16, 16), 256, 0, stream>>>(Wih_h, hc_h, xpT, bih, bhh,
                                              512, 512, 1024, 1024, 0, 1);

    // recurrence: 64 blocks x 512 threads, fully weight-resident, phase-overlapped
    lstm_rec<<<64, 512, 0, stream>>>(Whh_h, xpT, h0, c0, seqp, out);
}

// Round 8
// 1268.825 us; speedup vs baseline: 1.3756x; 1.3756x over previous
//
#include <hip/hip_runtime.h>
#include <stdint.h>

typedef __attribute__((ext_vector_type(4))) float f32x4;
typedef __attribute__((ext_vector_type(8))) _Float16 f16x8;

static __device__ __forceinline__ unsigned short f2h(float f) {
    union { _Float16 h; unsigned short u; } v;
    v.h = (_Float16)f;                      // v_cvt_f16_f32, RNE
    return v.u;
}
static __device__ __forceinline__ f16x8 as_f16x8(uint4 v) {
    union { uint4 u; f16x8 s; } x; x.u = v; return x.s;
}
static __device__ __forceinline__ float sigmoid_fast(float x) {
    return __builtin_amdgcn_rcpf(1.0f + __builtin_amdgcn_exp2f(-1.4426950408889634f * x));
}
static __device__ __forceinline__ float tanh_fast(float x) {
    return 1.0f - 2.0f * __builtin_amdgcn_rcpf(1.0f + __builtin_amdgcn_exp2f(2.8853900817779268f * x));
}
// barrier that waits only LDS (lgkmcnt(0)), NOT vmcnt — global stores keep retiring async.
static __device__ __forceinline__ void lds_barrier() {
    __builtin_amdgcn_s_waitcnt(0xc07f);
    __builtin_amdgcn_s_barrier();
}

// ---------- fused fp32 -> fp16 conversion for all 6 tensors (1 dispatch) ----------
__global__ __launch_bounds__(256) void convert_all(
    const float* __restrict__ h, const float* __restrict__ c,
    const float* __restrict__ iWh, const float* __restrict__ iWc,
    const float* __restrict__ Wih, const float* __restrict__ Whh,
    unsigned short* __restrict__ hc_h, unsigned short* __restrict__ iWh_h,
    unsigned short* __restrict__ iWc_h, unsigned short* __restrict__ Wih_h,
    unsigned short* __restrict__ Whh_h) {
    int i = blockIdx.x * 256 + threadIdx.x;      // float4 index, total 589824
    const float* src; unsigned short* dst;
    if (i < 131072) {            // h -> hc[:, 0:512]
        int base = i * 4, r = base >> 9, cc = base & 511;
        src = h + base; dst = hc_h + r * 1024 + cc;
    } else if (i < 262144) {     // c -> hc[:, 512:1024]
        int j = i - 131072; int base = j * 4, r = base >> 9, cc = base & 511;
        src = c + base; dst = hc_h + r * 1024 + 512 + cc;
    } else if (i < 327680) { int j = i - 262144; src = iWh + j * 4; dst = iWh_h + j * 4; }
    else if (i < 393216)   { int j = i - 327680; src = iWc + j * 4; dst = iWc_h + j * 4; }
    else if (i < 524288)   { int j = i - 393216; src = Wih + j * 4; dst = Wih_h + j * 4; }
    else                   { int j = i - 524288; src = Whh + j * 4; dst = Whh_h + j * 4; }
    float4 v = *(const float4*)src;
    dst[0] = f2h(v.x); dst[1] = f2h(v.y); dst[2] = f2h(v.z); dst[3] = f2h(v.w);
}

// ---------- generic C[M,N] = A[M,lda] @ W[N,ldw(:K)]^T + bias (+ELU), fp16 in / fp32 out ----
__global__ __launch_bounds__(256) void gemm_bt(
    const unsigned short* __restrict__ A, const unsigned short* __restrict__ W,
    float* __restrict__ C, const float* __restrict__ b1, const float* __restrict__ b2,
    int K, int lda, int ldw, int N, int do_elu, int bias_row) {
    __shared__ unsigned short As[64][40];
    __shared__ unsigned short Bs[64][40];
    int tid = threadIdx.x;
    int lane = tid & 63, wv = tid >> 6;
    int q = lane >> 4, l15 = lane & 15;
    int Mbase = blockIdx.x * 64, Nbase = blockIdx.y * 64;
    int ldrow = tid >> 2, seg = tid & 3;
    const unsigned short* Ap = A + (size_t)(Mbase + ldrow) * lda + seg * 8;
    const unsigned short* Wp = W + (size_t)(Nbase + ldrow) * ldw + seg * 8;
    f32x4 acc[4] = {};
    for (int k0 = 0; k0 < K; k0 += 32) {
        uint4 av = *(const uint4*)(Ap + k0);
        uint4 wvv = *(const uint4*)(Wp + k0);
        __syncthreads();
        *(uint4*)(&As[ldrow][seg * 8]) = av;
        *(uint4*)(&Bs[ldrow][seg * 8]) = wvv;
        __syncthreads();
        f16x8 af = *(const f16x8*)(&As[wv * 16 + l15][q * 8]);
#pragma unroll
        for (int nt = 0; nt < 4; nt++) {
            f16x8 bf = *(const f16x8*)(&Bs[nt * 16 + l15][q * 8]);
            acc[nt] = __builtin_amdgcn_mfma_f32_16x16x32_f16(af, bf, acc[nt], 0, 0, 0);
        }
    }
#pragma unroll
    for (int nt = 0; nt < 4; nt++) {
        int col = Nbase + nt * 16 + l15;
        float bcol = bias_row ? 0.0f : (b1[col] + (b2 ? b2[col] : 0.0f));
#pragma unroll
        for (int r = 0; r < 4; r++) {
            int row = Mbase + wv * 16 + q * 4 + r;
            float bias = bias_row ? (b1[row] + (b2 ? b2[row] : 0.0f)) : bcol;
            float v = acc[nt][r] + bias;
            if (do_elu) v = v > 0.0f ? v : (__builtin_amdgcn_exp2f(1.4426950408889634f * v) - 1.0f);
            C[(size_t)row * N + col] = v;
        }
    }
}

// ---------- fused init-state GEMMs (h0 and c0 via blockIdx.z), K=1024, N=256, ELU ----------
__global__ __launch_bounds__(256) void gemm_init(
    const unsigned short* __restrict__ A,
    const unsigned short* __restrict__ W0, const unsigned short* __restrict__ W1,
    float* __restrict__ C0, float* __restrict__ C1,
    const float* __restrict__ bias0, const float* __restrict__ bias1) {
    const unsigned short* W = blockIdx.z ? W1 : W0;
    float* C = blockIdx.z ? C1 : C0;
    const float* bias = blockIdx.z ? bias1 : bias0;
    __shared__ unsigned short As[64][40];
    __shared__ unsigned short Bs[64][40];
    int tid = threadIdx.x;
    int lane = tid & 63, wv = tid >> 6;
    int q = lane >> 4, l15 = lane & 15;
    int Mbase = blockIdx.x * 64, Nbase = blockIdx.y * 64;
    int ldrow = tid >> 2, seg = tid & 3;
    const unsigned short* Ap = A + (size_t)(Mbase + ldrow) * 1024 + seg * 8;
    const unsigned short* Wp = W + (size_t)(Nbase + ldrow) * 1024 + seg * 8;
    f32x4 acc[4] = {};
    for (int k0 = 0; k0 < 1024; k0 += 32) {
        uint4 av = *(const uint4*)(Ap + k0);
        uint4 wvv = *(const uint4*)(Wp + k0);
        __syncthreads();
        *(uint4*)(&As[ldrow][seg * 8]) = av;
        *(uint4*)(&Bs[ldrow][seg * 8]) = wvv;
        __syncthreads();
        f16x8 af = *(const f16x8*)(&As[wv * 16 + l15][q * 8]);
#pragma unroll
        for (int nt = 0; nt < 4; nt++) {
            f16x8 bf = *(const f16x8*)(&Bs[nt * 16 + l15][q * 8]);
            acc[nt] = __builtin_amdgcn_mfma_f32_16x16x32_f16(af, bf, acc[nt], 0, 0, 0);
        }
    }
#pragma unroll
    for (int nt = 0; nt < 4; nt++) {
        int col = Nbase + nt * 16 + l15;
        float b = bias[col];
#pragma unroll
        for (int r = 0; r < 4; r++) {
            int row = Mbase + wv * 16 + q * 4 + r;
            float v = acc[nt][r] + b;
            v = v > 0.0f ? v : (__builtin_amdgcn_exp2f(1.4426950408889634f * v) - 1.0f);
            C[(size_t)row * 256 + col] = v;
        }
    }
}

// ---------- persistent recurrent kernel: 64 blocks x 512 thr, 16 rows/block ----------
// FULL Whh residency, now split 48 frags in regs (kt0-5, all p) + 16 in LDS (kt6,kt7) with
// EXPLICIT READ PIPELINING. r5-r7 post-mortem: only ~12 free VGPRs existed (wreg188+acc32+
// xph16+creg8), so the compiler serialized all 25 per-step ds_reads as read->wait(~120cyc)
// ->use — ~6000 cyc/step of exposed LDS latency (MfmaUtil 5%, matrix pipe 75% idle).
// The r5<->r6 null (1067 vs 1065) proved per-step xpT global reloads are FREE, so xph's
// 16 regs are reallocated to: lw[4] weight window (16) + 2-slot af window (8).
// 10-slot MFMA schedule, every ds_read issued >=1 slot (~155 cyc) before use; next step's
// first weight group issues BEFORE the barrier (weight LDS is immutable):
//  S1:kt0(afA) S2:kt1(afB) S3:kt6p0-3(lw) S4:kt2 S5:kt6p4-7 S6:kt3 S7:kt7p0-3 S8:kt4
//  S9:kt7p4-7(+issue next G0) S10:kt5 -> EW -> acc prefetch (xpT) -> stores -> barrier.
#define HB_STRIDE 264                    // fp16 elems per h row (33x16B)
#define HB_HALF   (16 * HB_STRIDE)      // one h buffer, elems
#define WLDS_OFF  (2 * HB_HALF * 2)     // bytes: 16896
#define WFRAGS    16                     // LDS weight frags per wave (kt6, kt7)
#define LSTM_LDS_BYTES (WLDS_OFF + 8 * WFRAGS * 1024)   // 147968 <= 163840

__global__ __launch_bounds__(512, 2) void lstm_rec(
    const unsigned short* __restrict__ Whh,   // [1024,256] fp16
    const float* __restrict__ xpT,            // [1024 gatecols, 1024 rows] fp32
    const float* __restrict__ h0,             // [1024,256]
    const float* __restrict__ c0,             // [1024,256]
    const int* __restrict__ seq_len,
    float* __restrict__ out)                  // [1024, T, 256]
{
    __shared__ uint4 smem4[LSTM_LDS_BYTES / 16];
    unsigned short* hbuf = (unsigned short*)smem4;           // [2][16][HB_STRIDE]
    unsigned char* wlds = (unsigned char*)smem4 + WLDS_OFF;  // 8 waves * 16 frags * 1 KB
    const int tid = threadIdx.x;
    const int lane = tid & 63, wv = tid >> 6;   // wv 0..7
    const int q = lane >> 4, l15 = lane & 15;
    const int T = *seq_len;
    const int rowbase = blockIdx.x * 16;

    {   // h0 -> hbuf[0] rows 0..15 as fp16 (512 thr * 8 elems = 16*256 exactly)
        int e = tid * 8;
        int r = e >> 8, cc = e & 255;
        const float* s = h0 + (size_t)(rowbase + r) * 256 + cc;
        float4 v0 = *(const float4*)s;
        float4 v1 = *(const float4*)(s + 4);
        unsigned short* d = hbuf + r * HB_STRIDE + cc;
        d[0] = f2h(v0.x); d[1] = f2h(v0.y); d[2] = f2h(v0.z); d[3] = f2h(v0.w);
        d[4] = f2h(v1.x); d[5] = f2h(v1.y); d[6] = f2h(v1.z); d[7] = f2h(v1.w);
    }

    // weight fragment (kt,g,ct): elem = g*65536 + wv*8192 + ct*4096 + l15*256 + kt*32 + q*8
    const unsigned short* wb = Whh + wv * 8192 + l15 * 256 + q * 8;

    // 48 frags -> registers: fi = kt*8 + p (kt 0..5, p = g*2+ct)
    uint4 wreg[48];
#pragma unroll
    for (int kt = 0; kt < 6; kt++)
#pragma unroll
        for (int p = 0; p < 8; p++)
            wreg[kt * 8 + p] = *(const uint4*)(wb + (size_t)(p >> 1) * 65536 + (p & 1) * 4096 + kt * 32);

    // 16 frags -> LDS: slot = (kt-6)*8 + p; lane-linear 16B (conflict-free b128)
    unsigned char* wlp = wlds + wv * (WFRAGS * 1024) + lane * 16;
#pragma unroll
    for (int fi = 0; fi < WFRAGS; fi++) {
        int kt = 6 + (fi >> 3), p = fi & 7;
        uint4 v = *(const uint4*)(wb + (size_t)(p >> 1) * 65536 + (p & 1) * 4096 + kt * 32);
        *(uint4*)(wlp + fi * 1024) = v;
    }

    // c0 -> 8 f32 regs
    float creg[8];
#pragma unroll
    for (int ct = 0; ct < 2; ct++)
#pragma unroll
        for (int r = 0; r < 4; r++)
            creg[ct * 4 + r] = c0[(size_t)(rowbase + q * 4 + r) * 256 + wv * 32 + ct * 16 + l15];

    // x-proj base; acc[p] reloads from here every step (L2-resident, ~full-step lead; the
    // r5<->r6 null proved this costs nothing)
    const float* xpb = xpT + (size_t)(wv * 32 + l15) * 1024 + rowbase + (q << 2);
    f32x4 acc[8];
#pragma unroll
    for (int p = 0; p < 8; p++)
        acc[p] = *(const f32x4*)(xpb + (size_t)(p >> 1) * 262144 + (p & 1) * 16384);

    float* outp = out + ((size_t)(rowbase + q * 4) * T) * 256 + wv * 32 + l15;

    // weight window: preload G0 (kt6 p0-3) before the loop
    uint4 lw[4];
#pragma unroll
    for (int j = 0; j < 4; j++) lw[j] = *(const uint4*)(wlp + j * 1024);

    __syncthreads();

    for (int t = 0; t < T; t++) {
        const unsigned short* hb = hbuf + (t & 1) * HB_HALF + l15 * HB_STRIDE + q * 8;
        f16x8 afA, afB;
        afA = *(const f16x8*)(hb + 0 * 32);                 // af0
        afB = *(const f16x8*)(hb + 1 * 32);                 // af1
        // S1: kt0 (regs, afA); then afA <- af6
#pragma unroll
        for (int p = 0; p < 8; p++)
            acc[p] = __builtin_amdgcn_mfma_f32_16x16x32_f16(afA, as_f16x8(wreg[0 * 8 + p]), acc[p], 0, 0, 0);
        afA = *(const f16x8*)(hb + 6 * 32);
        // S2: kt1 (regs, afB); then afB <- af2
#pragma unroll
        for (int p = 0; p < 8; p++)
            acc[p] = __builtin_amdgcn_mfma_f32_16x16x32_f16(afB, as_f16x8(wreg[1 * 8 + p]), acc[p], 0, 0, 0);
        afB = *(const f16x8*)(hb + 2 * 32);
        // S3: kt6 p0-3 (lw = G0, afA=af6); then lw <- G1 (kt6 p4-7)
#pragma unroll
        for (int j = 0; j < 4; j++)
            acc[j] = __builtin_amdgcn_mfma_f32_16x16x32_f16(afA, as_f16x8(lw[j]), acc[j], 0, 0, 0);
#pragma unroll
        for (int j = 0; j < 4; j++) lw[j] = *(const uint4*)(wlp + (4 + j) * 1024);
        // S4: kt2 (regs, afB); then afB <- af3
#pragma unroll
        for (int p = 0; p < 8; p++)
            acc[p] = __builtin_amdgcn_mfma_f32_16x16x32_f16(afB, as_f16x8(wreg[2 * 8 + p]), acc[p], 0, 0, 0);
        afB = *(const f16x8*)(hb + 3 * 32);
        // S5: kt6 p4-7 (lw = G1, afA=af6); then lw <- G2 (kt7 p0-3), afA <- af7
#pragma unroll
        for (int j = 0; j < 4; j++)
            acc[4 + j] = __builtin_amdgcn_mfma_f32_16x16x32_f16(afA, as_f16x8(lw[j]), acc[4 + j], 0, 0, 0);
#pragma unroll
        for (int j = 0; j < 4; j++) lw[j] = *(const uint4*)(wlp + (8 + j) * 1024);
        afA = *(const f16x8*)(hb + 7 * 32);
        // S6: kt3 (regs, afB); then afB <- af4
#pragma unroll
        for (int p = 0; p < 8; p++)
            acc[p] = __builtin_amdgcn_mfma_f32_16x16x32_f16(afB, as_f16x8(wreg[3 * 8 + p]), acc[p], 0, 0, 0);
        afB = *(const f16x8*)(hb + 4 * 32);
        // S7: kt7 p0-3 (lw = G2, afA=af7); then lw <- G3 (kt7 p4-7)
#pragma unroll
        for (int j = 0; j < 4; j++)
            acc[j] = __builtin_amdgcn_mfma_f32_16x16x32_f16(afA, as_f16x8(lw[j]), acc[j], 0, 0, 0);
#pragma unroll
        for (int j = 0; j < 4; j++) lw[j] = *(const uint4*)(wlp + (12 + j) * 1024);
        // S8: kt4 (regs, afB); then afB <- af5
#pragma unroll
        for (int p = 0; p < 8; p++)
            acc[p] = __builtin_amdgcn_mfma_f32_16x16x32_f16(afB, as_f16x8(wreg[4 * 8 + p]), acc[p], 0, 0, 0);
        afB = *(const f16x8*)(hb + 5 * 32);
        // S9: kt7 p4-7 (lw = G3, afA=af7); then lw <- next step's G0 (weight LDS immutable)
#pragma unroll
        for (int j = 0; j < 4; j++)
            acc[4 + j] = __builtin_amdgcn_mfma_f32_16x16x32_f16(afA, as_f16x8(lw[j]), acc[4 + j], 0, 0, 0);
#pragma unroll
        for (int j = 0; j < 4; j++) lw[j] = *(const uint4*)(wlp + j * 1024);
        // S10: kt5 (regs, afB)
#pragma unroll
        for (int p = 0; p < 8; p++)
            acc[p] = __builtin_amdgcn_mfma_f32_16x16x32_f16(afB, as_f16x8(wreg[5 * 8 + p]), acc[p], 0, 0, 0);

        // elementwise: consume acc (already includes xp) -> hv, update creg
        float hv[8];
#pragma unroll
        for (int ct = 0; ct < 2; ct++)
#pragma unroll
            for (int r = 0; r < 4; r++) {
                float ig = sigmoid_fast(acc[0 + ct][r]);
                float fg = sigmoid_fast(acc[2 + ct][r]);
                float gg = tanh_fast(acc[4 + ct][r]);
                float og = sigmoid_fast(acc[6 + ct][r]);
                float cn = fg * creg[ct * 4 + r] + ig * gg;
                creg[ct * 4 + r] = cn;
                hv[ct * 4 + r] = og * tanh_fast(cn);
            }
        // prefetch next step's acc from xpT (before any store enters the vmcnt FIFO)
#pragma unroll
        for (int p = 0; p < 8; p++)
            acc[p] = *(const f32x4*)(xpb + (size_t)(p >> 1) * 262144 + (p & 1) * 16384);
        __builtin_amdgcn_sched_barrier(0);   // keep loads issued ahead of the stores below
        // write next h (LDS), then ys (global; retires async — never waited)
        unsigned short* hn = hbuf + ((t + 1) & 1) * HB_HALF + (q * 4) * HB_STRIDE + wv * 32 + l15;
#pragma unroll
        for (int ct = 0; ct < 2; ct++)
#pragma unroll
            for (int r = 0; r < 4; r++)
                hn[r * HB_STRIDE + ct * 16] = f2h(hv[ct * 4 + r]);
#pragma unroll
        for (int ct = 0; ct < 2; ct++)
#pragma unroll
            for (int r = 0; r < 4; r++)
                outp[(size_t)r * T * 256 + ct * 16] = hv[ct * 4 + r];
        outp += 256;
        lds_barrier();
    }
}

extern "C" void kernel_launch(void* const* d_in, const int* in_sizes, int n_in,
                              void* d_out, int out_size, void* d_ws, size_t ws_size,
                              hipStream_t stream) {
    const float* h   = (const float*)d_in[0];
    const float* c   = (const float*)d_in[1];
    const int*   seqp= (const int*)d_in[2];
    const float* iWh = (const float*)d_in[3];
    const float* ibh = (const float*)d_in[4];
    const float* iWc = (const float*)d_in[5];
    const float* ibc = (const float*)d_in[6];
    const float* Wih = (const float*)d_in[7];
    const float* Whh = (const float*)d_in[8];
    const float* bih = (const float*)d_in[9];
    const float* bhh = (const float*)d_in[10];
    float* out = (float*)d_out;
    unsigned char* ws = (unsigned char*)d_ws;

    // workspace layout (16B-aligned)
    unsigned short* hc_h  = (unsigned short*)(ws + 0);        // [1024,1024] fp16 = 2 MB
    unsigned short* iWh_h = (unsigned short*)(ws + 2097152);  // [256,1024]
    unsigned short* iWc_h = (unsigned short*)(ws + 2621440);  // [256,1024]
    unsigned short* Wih_h = (unsigned short*)(ws + 3145728);  // [1024,512]
    unsigned short* Whh_h = (unsigned short*)(ws + 4194304);  // [1024,256]
    float* h0  = (float*)(ws + 4718592);                       // [1024,256]
    float* c0  = (float*)(ws + 5767168);                       // [1024,256]
    float* xpT = (float*)(ws + 6815744);                       // [1024 gatecols,1024 rows]

    // fp16 conversions: all 6 tensors in one dispatch
    convert_all<<<2304, 256, 0, stream>>>(h, c, iWh, iWc, Wih, Whh,
                                          hc_h, iWh_h, iWc_h, Wih_h, Whh_h);

    // init states (fused pair) + transposed x_proj:
    // xpT[gatecol, batch] = Wih[gatecol,:] . h[batch,:] + bih[gatecol] + bhh[gatecol]
    gemm_init<<<dim3(16, 4, 2), 256, 0, stream>>>(hc_h, iWh_h, iWc_h, h0, c0, ibh, ibc);
    gemm_bt<<<dim3(16, 16), 256, 0, stream>>>(Wih_h, hc_h, xpT, bih, bhh,
                                              512, 512, 1024, 1024, 0, 1);

    // recurrence: 64 blocks x 512 threads, weight-resident, pipelined LDS reads
    lstm_rec<<<64, 512, 0, stream>>>(Whh_h, xpT, h0, c0, seqp, out);
}